// Round 3
// baseline (722.114 us; speedup 1.0000x reference)
//
#include <hip/hip_runtime.h>

typedef unsigned short u16;
typedef __attribute__((ext_vector_type(4))) float f32x4;
typedef __attribute__((ext_vector_type(8))) short short8;

#define MFMA16(a,b,c) __builtin_amdgcn_mfma_f32_16x16x32_bf16((a),(b),(c),0,0,0)

__device__ __forceinline__ u16 f2bf(float f){
  unsigned u = __float_as_uint(f);
  u += 0x7fffu + ((u>>16)&1u);
  return (u16)(u>>16);
}
__device__ __forceinline__ float bf2f(u16 s){ return __uint_as_float(((unsigned)s)<<16); }

__device__ __forceinline__ void glds16(const void* g, void* l){
  __builtin_amdgcn_global_load_lds(
    (const __attribute__((address_space(1))) unsigned int*)g,
    (__attribute__((address_space(3))) unsigned int*)l, 16, 0, 0);
}

// ---------------- prep kernels ----------------

// hidden (8,388,608 floats) -> Hh, Hl bf16 (split)
__global__ __launch_bounds__(256) void k_split_hidden(const float4* __restrict__ H,
    u16* __restrict__ Hh, u16* __restrict__ Hl){
  int i = blockIdx.x*256 + threadIdx.x;
  float4 v = H[i];
  u16 h0=f2bf(v.x), h1=f2bf(v.y), h2=f2bf(v.z), h3=f2bf(v.w);
  ushort4 hi = make_ushort4(h0,h1,h2,h3);
  ushort4 lo = make_ushort4(f2bf(v.x-bf2f(h0)), f2bf(v.y-bf2f(h1)),
                            f2bf(v.z-bf2f(h2)), f2bf(v.w-bf2f(h3)));
  *(ushort4*)(Hh + (size_t)i*4) = hi;
  *(ushort4*)(Hl + (size_t)i*4) = lo;
}

// transpose Wq/Wk/Wv to B^T layout [n][k]; split q,k into hi/lo
__global__ __launch_bounds__(256) void k_prep_w3(
    const float* __restrict__ Wq, const float* __restrict__ Wk, const float* __restrict__ Wv,
    u16* __restrict__ Wqh, u16* __restrict__ Wql,
    u16* __restrict__ Wkh, u16* __restrict__ Wkl, u16* __restrict__ Wvh){
  int z = blockIdx.z;
  const float* W = (z==0)?Wq:((z==1)?Wk:Wv);
  __shared__ float tile[64][65];
  int k0 = blockIdx.x*64, n0 = blockIdx.y*64;
  int t = threadIdx.x;
  #pragma unroll 4
  for (int i=0;i<16;i++){
    int idx = t + i*256; int r = idx>>6, c = idx&63;
    tile[r][c] = W[(size_t)(k0+r)*2048 + n0 + c];
  }
  __syncthreads();
  #pragma unroll 4
  for (int i=0;i<16;i++){
    int idx = t + i*256; int r = idx>>6, c = idx&63;
    float v = tile[c][r];
    u16 hi = f2bf(v);
    size_t o = (size_t)(n0+r)*2048 + k0 + c;
    if (z==0){ Wqh[o]=hi; Wql[o]=f2bf(v - bf2f(hi)); }
    else if (z==1){ Wkh[o]=hi; Wkl[o]=f2bf(v - bf2f(hi)); }
    else { Wvh[o]=hi; }
  }
}

// transpose one weight (hi only) — used for Wo after Wq buffer is dead
__global__ __launch_bounds__(256) void k_prep_w1(const float* __restrict__ W,
    u16* __restrict__ hiT){
  __shared__ float tile[64][65];
  int k0 = blockIdx.x*64, n0 = blockIdx.y*64;
  int t = threadIdx.x;
  #pragma unroll 4
  for (int i=0;i<16;i++){
    int idx = t + i*256; int r = idx>>6, c = idx&63;
    tile[r][c] = W[(size_t)(k0+r)*2048 + n0 + c];
  }
  __syncthreads();
  #pragma unroll 4
  for (int i=0;i<16;i++){
    int idx = t + i*256; int r = idx>>6, c = idx&63;
    hiT[(size_t)(n0+r)*2048 + k0 + c] = f2bf(tile[c][r]);
  }
}

// cos/sin tables: [2048][64] fp32
__global__ __launch_bounds__(256) void k_rope_tab(const int* __restrict__ pos,
    float* __restrict__ ct, float* __restrict__ st){
  int i = blockIdx.x*256 + threadIdx.x;
  int s = i>>6, j = i&63;
  float p = (float)pos[s];
  float inv = exp2f(-(float)j * 0.20762050593046014f);  // log2(10000)/64
  float a = p*inv;
  ct[i] = cosf(a); st[i] = sinf(a);
}

// ---------------- fused Q/K GEMM + RoPE epilogue ----------------
// wave tile 32x128 (4 waves stack M). Block N-tile = one head (128 cols) so
// rope pairs (d, d+64) are acc cols (ni, ni+4) in the SAME lane.
__global__ __launch_bounds__(256) void k_gemm_qk(
    const u16* __restrict__ Hh, const u16* __restrict__ Hl,
    const u16* __restrict__ Wqh, const u16* __restrict__ Wql,
    const u16* __restrict__ Wkh, const u16* __restrict__ Wkl,
    const float* __restrict__ ct, const float* __restrict__ st,
    u16* __restrict__ Qh, u16* __restrict__ Ql,
    u16* __restrict__ Kh, u16* __restrict__ Kl)
{
  int z = blockIdx.z;
  const u16* Bh = z ? Wkh : Wqh;
  const u16* Bl = z ? Wkl : Wql;
  u16* Oh = z ? Kh : Qh;
  u16* Ol = z ? Kl : Ql;
  __shared__ __align__(16) u16 lAh[128*32], lAl[128*32], lBh[128*32], lBl[128*32];
  int m0 = blockIdx.x*128, h = blockIdx.y;
  int tid = threadIdx.x, lane = tid&63, w = tid>>6;
  int g = lane>>4, r = lane&15;
  f32x4 acc[2][8];
  #pragma unroll
  for (int i=0;i<2;i++)
    #pragma unroll
    for (int j=0;j<8;j++)
      #pragma unroll
      for (int e=0;e<4;e++) acc[i][j][e]=0.f;

  for (int k0=0;k0<2048;k0+=32){
    __syncthreads();
    #pragma unroll
    for (int c=0;c<2;c++){
      int off = (w*2+c)*1024 + lane*16;
      int row = off>>6, colb = off&63;
      size_t ga = ((size_t)(m0+row)*2048 + k0)*2 + colb;
      size_t gb = ((size_t)(h*128+row)*2048 + k0)*2 + colb;
      int lo = (w*2+c)*1024;
      glds16((const char*)Hh + ga, (char*)lAh + lo);
      glds16((const char*)Hl + ga, (char*)lAl + lo);
      glds16((const char*)Bh + gb, (char*)lBh + lo);
      glds16((const char*)Bl + gb, (char*)lBl + lo);
    }
    asm volatile("s_waitcnt vmcnt(0)" ::: "memory");
    __syncthreads();
    short8 a_h[2], a_l[2];
    #pragma unroll
    for (int mi=0;mi<2;mi++){
      int row = w*32 + mi*16 + r;
      a_h[mi] = *(const short8*)((const char*)lAh + row*64 + g*16);
      a_l[mi] = *(const short8*)((const char*)lAl + row*64 + g*16);
    }
    #pragma unroll
    for (int ni=0;ni<8;ni++){
      int row = ni*16 + r;
      short8 b_h = *(const short8*)((const char*)lBh + row*64 + g*16);
      short8 b_l = *(const short8*)((const char*)lBl + row*64 + g*16);
      #pragma unroll
      for (int mi=0;mi<2;mi++){
        acc[mi][ni] = MFMA16(a_h[mi], b_h, acc[mi][ni]);
        acc[mi][ni] = MFMA16(a_h[mi], b_l, acc[mi][ni]);
        acc[mi][ni] = MFMA16(a_l[mi], b_h, acc[mi][ni]);
      }
    }
  }
  // epilogue: RoPE + split hi/lo, store (bh, s, d)
  int b = m0>>11;
  int bh = b*16 + h;
  #pragma unroll
  for (int mi=0;mi<2;mi++){
    #pragma unroll
    for (int rr=0;rr<4;rr++){
      int s = (m0&2047) + w*32 + mi*16 + g*4 + rr;
      size_t rowbase = ((size_t)bh*2048 + s)*128;
      #pragma unroll
      for (int ni=0;ni<4;ni++){
        int j = ni*16 + r;
        float c = ct[s*64 + j], sn = st[s*64 + j];
        float x1 = acc[mi][ni][rr], x2 = acc[mi][ni+4][rr];
        float o1 = x1*c - x2*sn;
        float o2 = x2*c + x1*sn;
        u16 h1 = f2bf(o1); Oh[rowbase + j] = h1;      Ol[rowbase + j]      = f2bf(o1 - bf2f(h1));
        u16 h2 = f2bf(o2); Oh[rowbase + 64 + j] = h2; Ol[rowbase + 64 + j] = f2bf(o2 - bf2f(h2));
      }
    }
  }
}

// ---------------- V GEMM (1-term bf16) with transposed epilogue -> VT (bh,d,s) ----------------
__global__ __launch_bounds__(256) void k_gemm_v(
    const u16* __restrict__ Hh, const u16* __restrict__ Wvh, u16* __restrict__ VT)
{
  __shared__ __align__(16) u16 lA[128*32], lB[128*32];
  int m0 = blockIdx.x*128, h = blockIdx.y;
  int tid = threadIdx.x, lane = tid&63, w = tid>>6;
  int g = lane>>4, r = lane&15;
  f32x4 acc[2][8];
  #pragma unroll
  for (int i=0;i<2;i++)
    #pragma unroll
    for (int j=0;j<8;j++)
      #pragma unroll
      for (int e=0;e<4;e++) acc[i][j][e]=0.f;
  for (int k0=0;k0<2048;k0+=32){
    __syncthreads();
    #pragma unroll
    for (int c=0;c<2;c++){
      int off = (w*2+c)*1024 + lane*16;
      int row = off>>6, colb = off&63;
      size_t ga = ((size_t)(m0+row)*2048 + k0)*2 + colb;
      size_t gb = ((size_t)(h*128+row)*2048 + k0)*2 + colb;
      int lo = (w*2+c)*1024;
      glds16((const char*)Hh + ga, (char*)lA + lo);
      glds16((const char*)Wvh + gb, (char*)lB + lo);
    }
    asm volatile("s_waitcnt vmcnt(0)" ::: "memory");
    __syncthreads();
    short8 a_h[2];
    #pragma unroll
    for (int mi=0;mi<2;mi++){
      int row = w*32 + mi*16 + r;
      a_h[mi] = *(const short8*)((const char*)lA + row*64 + g*16);
    }
    #pragma unroll
    for (int ni=0;ni<8;ni++){
      int row = ni*16 + r;
      short8 b_h = *(const short8*)((const char*)lB + row*64 + g*16);
      #pragma unroll
      for (int mi=0;mi<2;mi++)
        acc[mi][ni] = MFMA16(a_h[mi], b_h, acc[mi][ni]);
    }
  }
  int b = m0>>11;
  int bh = b*16 + h;
  #pragma unroll
  for (int mi=0;mi<2;mi++){
    int sb = (m0&2047) + w*32 + mi*16 + g*4;
    #pragma unroll
    for (int ni=0;ni<8;ni++){
      int d = ni*16 + r;
      ushort4 vv = make_ushort4(f2bf(acc[mi][ni][0]), f2bf(acc[mi][ni][1]),
                                f2bf(acc[mi][ni][2]), f2bf(acc[mi][ni][3]));
      *(ushort4*)(VT + ((size_t)(bh*128 + d))*2048 + sb) = vv;
    }
  }
}

// ---------------- flash attention v2 ----------------
// grid (32 q-tiles, 32 bh), 4 waves x 16 q-rows, KVBLK=32, LDS 29.7KB -> 5 blocks/CU
__global__ __launch_bounds__(256) void k_attn(
  const u16* __restrict__ Qh, const u16* __restrict__ Ql,
  const u16* __restrict__ Kh, const u16* __restrict__ Kl,
  const u16* __restrict__ VT, u16* __restrict__ AO)
{
  __shared__ __align__(16) u16 lKh[32*128], lKl[32*128], lVT[128*32];
  __shared__ __align__(16) u16 lP[4*16*40];   // row stride 40 u16 = 80B (16B-aligned)
  int bh = blockIdx.y, q0 = blockIdx.x*64;
  int tid = threadIdx.x, lane = tid&63, w = tid>>6;
  int g = lane>>4, r = lane&15;
  const float SC = 0.12751878329866064f;  // log2(e)/sqrt(128)
  short8 qh[4], ql[4];
  {
    size_t qb = ((size_t)bh*2048 + q0 + w*16 + r)*128;
    #pragma unroll
    for (int ks=0;ks<4;ks++){
      qh[ks] = *(const short8*)(Qh + qb + ks*32 + g*8);
      ql[ks] = *(const short8*)(Ql + qb + ks*32 + g*8);
    }
  }
  // hoisted swizzled K read offsets (kv-invariant): addr = ni*4096 + koff[ks]
  int koff[4];
  #pragma unroll
  for (int ks=0;ks<4;ks++){
    int ch = ks*4 + g;
    koff[ks] = r*256 + (((ch&8) | ((ch^r)&7))<<4);
  }
  f32x4 o[8];
  #pragma unroll
  for (int i=0;i<8;i++)
    #pragma unroll
    for (int e=0;e<4;e++) o[i][e]=0.f;
  float mrow[4] = {-3.0e38f,-3.0e38f,-3.0e38f,-3.0e38f};
  float lrowl[4] = {0.f,0.f,0.f,0.f};          // lane-local l accumulator
  size_t kb = (size_t)bh*2048*128;
  size_t vbase = (size_t)bh*128*2048;

  for (int kv0=0;kv0<2048;kv0+=32){
    __syncthreads();
    #pragma unroll
    for (int c=0;c<2;c++){
      int off = (w*2+c)*1024 + lane*16;
      int lo = (w*2+c)*1024;
      int krow = off>>8, ch = (off>>4)&15;
      int chs = (ch&8)|((ch^krow)&7);                       // pre-swizzled source chunk
      size_t gk = (kb + (size_t)(kv0+krow)*128)*2 + chs*16;
      glds16((const char*)Kh + gk, (char*)lKh + lo);
      glds16((const char*)Kl + gk, (char*)lKl + lo);
      int vrow = off>>6, sch = (off>>4)&3;
      size_t gv = (vbase + (size_t)vrow*2048 + kv0 + sch*8)*2;
      glds16((const char*)VT + gv, (char*)lVT + lo);
    }
    asm volatile("s_waitcnt vmcnt(0)" ::: "memory");
    __syncthreads();

    f32x4 s4[2];
    #pragma unroll
    for (int i=0;i<2;i++)
      #pragma unroll
      for (int e=0;e<4;e++) s4[i][e]=0.f;
    __builtin_amdgcn_s_setprio(1);
    #pragma unroll
    for (int ks=0;ks<4;ks++){
      #pragma unroll
      for (int ni=0;ni<2;ni++){
        int a = ni*4096 + koff[ks];
        short8 kh8 = *(const short8*)((const char*)lKh + a);
        short8 kl8 = *(const short8*)((const char*)lKl + a);
        s4[ni] = MFMA16(qh[ks], kh8, s4[ni]);
        s4[ni] = MFMA16(qh[ks], kl8, s4[ni]);
        s4[ni] = MFMA16(ql[ks], kh8, s4[ni]);
      }
    }
    __builtin_amdgcn_s_setprio(0);
    // online softmax, rows = g*4+rr (uniform across 16-lane group)
    float pm[4];
    #pragma unroll
    for (int rr=0;rr<4;rr++){
      float m = fmaxf(s4[0][rr], s4[1][rr]);
      m = fmaxf(m, __shfl_xor(m,1));
      m = fmaxf(m, __shfl_xor(m,2));
      m = fmaxf(m, __shfl_xor(m,4));
      m = fmaxf(m, __shfl_xor(m,8));
      pm[rr]=m;
    }
    bool anynew = (pm[0]>mrow[0])|(pm[1]>mrow[1])|(pm[2]>mrow[2])|(pm[3]>mrow[3]);
    if (__any(anynew)){
      float f[4];
      #pragma unroll
      for (int rr=0;rr<4;rr++){
        float mn = fmaxf(mrow[rr], pm[rr]);
        f[rr] = exp2f((mrow[rr]-mn)*SC);
        mrow[rr]=mn; lrowl[rr]*=f[rr];
      }
      #pragma unroll
      for (int nd=0;nd<8;nd++)
        #pragma unroll
        for (int rr=0;rr<4;rr++) o[nd][rr] *= f[rr];
    }
    #pragma unroll
    for (int ni=0;ni<2;ni++){
      #pragma unroll
      for (int rr=0;rr<4;rr++){
        float p = exp2f((s4[ni][rr]-mrow[rr])*SC);
        lrowl[rr] += p;
        lP[w*640 + (g*4+rr)*40 + ni*16 + r] = f2bf(p);
      }
    }
    // PV (k=32 -> one MFMA per nd)
    short8 pa = *(const short8*)((const char*)lP + w*1280 + r*80 + g*16);
    __builtin_amdgcn_s_setprio(1);
    #pragma unroll
    for (int nd=0;nd<8;nd++){
      short8 v8 = *(const short8*)((const char*)lVT + (nd*16+r)*64 + g*16);
      o[nd] = MFMA16(pa, v8, o[nd]);
    }
    __builtin_amdgcn_s_setprio(0);
  }
  // reduce l across the 16-lane group (each lane held a col-subset)
  float lrow[4];
  #pragma unroll
  for (int rr=0;rr<4;rr++){
    float x = lrowl[rr];
    x += __shfl_xor(x,1); x += __shfl_xor(x,2);
    x += __shfl_xor(x,4); x += __shfl_xor(x,8);
    lrow[rr] = x;
  }
  int b = bh>>4, h = bh&15;
  #pragma unroll
  for (int rr=0;rr<4;rr++){
    float inv = 1.0f/lrow[rr];
    int row = b*2048 + q0 + w*16 + g*4 + rr;
    #pragma unroll
    for (int nd=0;nd<8;nd++){
      int col = h*128 + nd*16 + r;
      AO[(size_t)row*2048 + col] = f2bf(o[nd][rr]*inv);
    }
  }
}

// ---------------- out projection (bf16 A,B -> fp32 C) ----------------
__global__ __launch_bounds__(256) void k_gemm_out(
    const u16* __restrict__ A, const u16* __restrict__ Bt, float* __restrict__ C)
{
  __shared__ __align__(16) u16 lA[128*32], lB[128*32];
  int m0 = blockIdx.x*128, n0 = blockIdx.y*128;
  int tid = threadIdx.x, lane = tid&63, w = tid>>6;
  int wr = w>>1, wc = w&1, g = lane>>4, r = lane&15;
  f32x4 acc[4][4];
  #pragma unroll
  for (int i=0;i<4;i++)
    #pragma unroll
    for (int j=0;j<4;j++)
      #pragma unroll
      for (int e=0;e<4;e++) acc[i][j][e]=0.f;
  for (int k0=0;k0<2048;k0+=32){
    __syncthreads();
    #pragma unroll
    for (int c=0;c<2;c++){
      int off = (w*2+c)*1024 + lane*16;
      int row = off>>6, colb = off&63;
      size_t ga = ((size_t)(m0+row)*2048 + k0)*2 + colb;
      size_t gb = ((size_t)(n0+row)*2048 + k0)*2 + colb;
      int lo = (w*2+c)*1024;
      glds16((const char*)A + ga, (char*)lA + lo);
      glds16((const char*)Bt + gb, (char*)lB + lo);
    }
    asm volatile("s_waitcnt vmcnt(0)" ::: "memory");
    __syncthreads();
    short8 af[4];
    #pragma unroll
    for (int mi=0;mi<4;mi++){
      int row = wr*64 + mi*16 + r;
      af[mi] = *(const short8*)((const char*)lA + row*64 + g*16);
    }
    #pragma unroll
    for (int ni=0;ni<4;ni++){
      int row = wc*64 + ni*16 + r;
      short8 b8 = *(const short8*)((const char*)lB + row*64 + g*16);
      #pragma unroll
      for (int mi=0;mi<4;mi++)
        acc[mi][ni] = MFMA16(af[mi], b8, acc[mi][ni]);
    }
  }
  #pragma unroll
  for (int mi=0;mi<4;mi++){
    #pragma unroll
    for (int rr=0;rr<4;rr++){
      int row = m0 + wr*64 + mi*16 + g*4 + rr;
      #pragma unroll
      for (int ni=0;ni<4;ni++){
        int col = n0 + wc*64 + ni*16 + r;
        C[(size_t)row*2048+col] = acc[mi][ni][rr];
      }
    }
  }
}

extern "C" void kernel_launch(void* const* d_in, const int* in_sizes, int n_in,
                              void* d_out, int out_size, void* d_ws, size_t ws_size,
                              hipStream_t stream){
  const float* Hsrc = (const float*)d_in[0];
  const int*   pids = (const int*)d_in[1];
  const float* Wq   = (const float*)d_in[2];
  const float* Wk   = (const float*)d_in[3];
  const float* Wv   = (const float*)d_in[4];
  const float* Wo   = (const float*)d_in[5];
  float* out = (float*)d_out;

  // ---- workspace layout (peak ~137 MB) ----
  char* p = (char*)d_ws;
  u16* Hh  = (u16*)(p);                  // 16,777,216  -> AO after V-GEMM
  u16* Hl  = (u16*)(p +  16777216);      // 16,777,216  -> VT after QK-GEMM
  u16* Wqh = (u16*)(p +  33554432);      //  8,388,608  -> Woh after QK-GEMM
  u16* Wql = (u16*)(p +  41943040);      //  8,388,608
  u16* Wkh = (u16*)(p +  50331648);      //  8,388,608
  u16* Wkl = (u16*)(p +  58720256);      //  8,388,608
  u16* Wvh = (u16*)(p +  67108864);      //  8,388,608
  u16* Qsh = (u16*)(p +  75497472);      // 16,777,216
  u16* Qsl = (u16*)(p +  92274688);      // 16,777,216
  u16* Ksh = (u16*)(p + 109051904);      // 16,777,216
  u16* Ksl = (u16*)(p + 125829120);      // 16,777,216
  float* ct = (float*)(p + 142606336);   //    524,288
  float* st = (float*)(p + 143130624);   //    524,288
  u16* VT  = Hl;    // alias: Hl dead after QK-GEMM (V-GEMM reads only Hh)
  u16* AO  = Hh;    // alias: Hh dead after V-GEMM
  u16* Woh = Wqh;   // alias: Wqh dead after QK-GEMM

  k_split_hidden<<<8192,256,0,stream>>>((const float4*)Hsrc, Hh, Hl);
  k_rope_tab<<<512,256,0,stream>>>(pids, ct, st);
  k_prep_w3<<<dim3(32,32,3),256,0,stream>>>(Wq,Wk,Wv,Wqh,Wql,Wkh,Wkl,Wvh);
  k_gemm_qk<<<dim3(32,16,2),256,0,stream>>>(Hh,Hl,Wqh,Wql,Wkh,Wkl,ct,st,Qsh,Qsl,Ksh,Ksl);
  k_prep_w1<<<dim3(32,32),256,0,stream>>>(Wo, Woh);       // into dead Wqh region
  k_gemm_v<<<dim3(32,16),256,0,stream>>>(Hh, Wvh, VT);    // VT into dead Hl region
  k_attn<<<dim3(32,32),256,0,stream>>>(Qsh,Qsl,Ksh,Ksl,VT,AO);  // AO into dead Hh region
  k_gemm_out<<<dim3(32,16),256,0,stream>>>(AO, Woh, out);
}